// Round 7
// baseline (453.249 us; speedup 1.0000x reference)
//
#include <hip/hip_runtime.h>
#include <hip/hip_bf16.h>

#define T_ 128
#define N_ 1024
#define E_ 16384
#define D_ 256
#define H_ 8
#define D2_ 512    // 2*D
#define NB2_ 4096  // cell buckets: bucket = src*4 + (dst>>8), 256 cells each
#define PS2_ 129   // prefS2 row stride

typedef __attribute__((ext_vector_type(8))) short bf16x8;
typedef __attribute__((ext_vector_type(4))) float f32x4;

__device__ __forceinline__ void atomAddF(float* p, float v) {
#if defined(__HIP_PLATFORM_AMD__)
    unsafeAtomicAdd(p, v);
#else
    atomicAdd(p, v);
#endif
}

__device__ __forceinline__ unsigned short f2bf(float x) {
    return __bfloat16_as_ushort(__float2bfloat16(x));
}

// ---------------------------------------------------------------------------
// Kernel A0: cast W1 (f32 [256][512]) to bf16 in B-fragment-linear layout:
// W1S[(k8*512 + col)*8 + (k&7)]
// ---------------------------------------------------------------------------
__global__ __launch_bounds__(256)
void k_w1cast(const float* __restrict__ W1, unsigned short* __restrict__ W1S)
{
    const int u   = blockIdx.x * 256 + threadIdx.x;  // 0..16383
    const int col = u & 511;
    const int k8  = u >> 9;                          // 0..31
    unsigned short h[8];
    #pragma unroll
    for (int j = 0; j < 8; ++j)
        h[j] = f2bf(W1[(size_t)(k8 * 8 + j) * D2_ + col]);
    uint4 pk;
    pk.x = h[0] | ((unsigned)h[1] << 16);
    pk.y = h[2] | ((unsigned)h[3] << 16);
    pk.z = h[4] | ((unsigned)h[5] << 16);
    pk.w = h[6] | ((unsigned)h[7] << 16);
    *(uint4*)&W1S[(size_t)k8 * 4096 + col * 8] = pk;
}

// ---------------------------------------------------------------------------
// Kernel A: bf16 MFMA GEMM  h = relu(emb@W1+b1), fused in-register pooling.
// ZERO LDS / ZERO BARRIERS: A-frags loaded direct from emb (f32->bf16 in reg),
// B-frags loaded direct from fragment-linear W1S (L2-resident, contiguous
// 256B per 16 lanes). 8 waves (2M x 4N), tile M=64, N=512, full K unrolled.
// ---------------------------------------------------------------------------
__global__ __launch_bounds__(512)
void k_mlp1_mfma(const float* __restrict__ emb,
                 const unsigned short* __restrict__ W1S,
                 const float* __restrict__ b1,
                 float* __restrict__ pool_sum,        // [T][512]
                 unsigned int* __restrict__ pool_max) // [T][512] float-as-uint
{
    const int tid  = threadIdx.x;
    const int lane = tid & 63;
    const int wave = tid >> 6;
    const int wm = wave >> 2, wn = wave & 3;   // 2 x 4 wave grid
    const int l15 = lane & 15, l4 = lane >> 4;
    const int r0 = blockIdx.x * 64;            // global row = t*1024 + n
    const int t  = blockIdx.x >> 4;

    f32x4 acc[2][8] = {};

    const float* arow0 = emb + (size_t)(r0 + wm * 32 + l15) * D_;
    const float* arow1 = arow0 + 16 * D_;
    // B: W1S[((ks*4+l4)*512 + wn*128 + cf*16 + l15)*8]
    const unsigned short* bbase = W1S + ((size_t)l4 * 512 + wn * 128 + l15) * 8;

    #pragma unroll
    for (int ks = 0; ks < 8; ++ks) {
        const int koff = ks * 32 + l4 * 8;
        const float4 va0 = *(const float4*)&arow0[koff];
        const float4 va1 = *(const float4*)&arow0[koff + 4];
        const float4 vb0 = *(const float4*)&arow1[koff];
        const float4 vb1 = *(const float4*)&arow1[koff + 4];

        union { bf16x8 v; unsigned int u[4]; } a0, a1;
        a0.u[0] = f2bf(va0.x) | ((unsigned)f2bf(va0.y) << 16);
        a0.u[1] = f2bf(va0.z) | ((unsigned)f2bf(va0.w) << 16);
        a0.u[2] = f2bf(va1.x) | ((unsigned)f2bf(va1.y) << 16);
        a0.u[3] = f2bf(va1.z) | ((unsigned)f2bf(va1.w) << 16);
        a1.u[0] = f2bf(vb0.x) | ((unsigned)f2bf(vb0.y) << 16);
        a1.u[1] = f2bf(vb0.z) | ((unsigned)f2bf(vb0.w) << 16);
        a1.u[2] = f2bf(vb1.x) | ((unsigned)f2bf(vb1.y) << 16);
        a1.u[3] = f2bf(vb1.z) | ((unsigned)f2bf(vb1.w) << 16);

        const unsigned short* bk = bbase + (size_t)ks * 16384;
        #pragma unroll
        for (int cf = 0; cf < 8; ++cf) {
            const bf16x8 b = *(const bf16x8*)(bk + cf * 128);
            acc[0][cf] = __builtin_amdgcn_mfma_f32_16x16x32_bf16(a0.v, b, acc[0][cf], 0, 0, 0);
            acc[1][cf] = __builtin_amdgcn_mfma_f32_16x16x32_bf16(a1.v, b, acc[1][cf], 0, 0, 0);
        }
    }

    // epilogue: bias+relu, reduce rows in-register, atomics to pool
    #pragma unroll
    for (int cf = 0; cf < 8; ++cf) {
        const int col = wn * 128 + cf * 16 + l15;
        const float bias = b1[col];
        float cs = 0.f, cm = 0.f;
        #pragma unroll
        for (int mf = 0; mf < 2; ++mf) {
            #pragma unroll
            for (int j = 0; j < 4; ++j) {
                float h = acc[mf][cf][j] + bias;
                h = fmaxf(h, 0.f);
                cs += h;
                cm = fmaxf(cm, h);
            }
        }
        cs += __shfl_xor(cs, 16);
        cs += __shfl_xor(cs, 32);
        cm = fmaxf(cm, __shfl_xor(cm, 16));
        cm = fmaxf(cm, __shfl_xor(cm, 32));
        if (l4 == 0) {
            atomAddF(pool_sum + t * D2_ + col, cs);
            atomicMax(pool_max + t * D2_ + col, __float_as_uint(cm));
        }
    }
}

// ---------------------------------------------------------------------------
// Kernel B+C fused: pooled -> x (LDS only) -> q,k
// ---------------------------------------------------------------------------
__global__ __launch_bounds__(256)
void k_mlp2qk(const float* __restrict__ pool_sum,
              const unsigned int* __restrict__ pool_max,
              const float* __restrict__ W2, const float* __restrict__ b2,
              const float* __restrict__ Wq, const float* __restrict__ bq,
              const float* __restrict__ Wk, const float* __restrict__ bk,
              float* __restrict__ q, float* __restrict__ k)
{
    __shared__ float pl[D2_];
    __shared__ float xl[D_];
    const int t = blockIdx.x;
    const int j = threadIdx.x;

    pl[j]       = pool_sum[t * D2_ + j]       * (1.0f / (float)N_) +
                  __uint_as_float(pool_max[t * D2_ + j]);
    pl[j + 256] = pool_sum[t * D2_ + j + 256] * (1.0f / (float)N_) +
                  __uint_as_float(pool_max[t * D2_ + j + 256]);
    __syncthreads();

    float acc = b2[j];
    for (int kk = 0; kk < D2_; ++kk)
        acc += pl[kk] * W2[(size_t)kk * D_ + j];
    acc = fmaxf(acc, 0.f);

    const int i2 = (j >> 1) * 2;
    const float div = expf((float)i2 * (-logf(10000.0f) / (float)D_));
    const float ang = (float)t * div;
    acc += (j & 1) ? cosf(ang) : sinf(ang);
    xl[j] = acc;
    __syncthreads();

    float aq = bq[j], ak = bk[j];
    for (int kk = 0; kk < D_; ++kk) {
        const float xv = xl[kk];
        aq += xv * Wq[(size_t)kk * D_ + j];
        ak += xv * Wk[(size_t)kk * D_ + j];
    }
    q[t * D_ + j] = aq * 0.17677669529663687f;  // (D/H)^-0.5
    k[t * D_ + j] = ak;
}

// ---------------------------------------------------------------------------
// Kernel D: scores -> per-head softmax -> mean heads -> threshold/identity/tril
// ---------------------------------------------------------------------------
__global__ __launch_bounds__(128)
void k_probs(const float* __restrict__ q,
             const float* __restrict__ k,
             float* __restrict__ probs)
{
    __shared__ float ql[D_];
    __shared__ float red[128];
    const int qt = blockIdx.x;
    const int kt = threadIdx.x;

    ql[kt]       = q[qt * D_ + kt];
    ql[kt + 128] = q[qt * D_ + kt + 128];
    __syncthreads();

    float sh[H_];
    #pragma unroll
    for (int h = 0; h < H_; ++h) {
        float s = 0.f;
        #pragma unroll
        for (int d = 0; d < 32; ++d)
            s += ql[h * 32 + d] * k[kt * D_ + h * 32 + d];
        sh[h] = s;
    }

    float pm = 0.f;
    for (int h = 0; h < H_; ++h) {
        red[kt] = sh[h]; __syncthreads();
        for (int off = 64; off > 0; off >>= 1) {
            if (kt < off) red[kt] = fmaxf(red[kt], red[kt + off]);
            __syncthreads();
        }
        const float m = red[0]; __syncthreads();
        const float e = expf(sh[h] - m);
        red[kt] = e; __syncthreads();
        for (int off = 64; off > 0; off >>= 1) {
            if (kt < off) red[kt] += red[kt + off];
            __syncthreads();
        }
        const float Z = red[0]; __syncthreads();
        pm += e / Z;
    }
    pm *= (1.0f / (float)H_);

    if (pm < (1.0f / (float)T_)) pm = 0.f;
    if (kt == qt) pm += 1.0f;
    if (kt > qt) pm = 0.f;
    probs[qt * T_ + kt] = pm;
}

// ---------------------------------------------------------------------------
// Kernel D2: pack probs f32 -> bf16 a-fragment-linear Pfrag[kc][tf][lane][8]
// ---------------------------------------------------------------------------
__global__ __launch_bounds__(256)
void k_pcast(const float* __restrict__ probs, unsigned short* __restrict__ Pfrag)
{
    const int u    = blockIdx.x * 256 + threadIdx.x;  // 0..2047
    const int lane = u & 63;
    const int tf   = (u >> 6) & 7;
    const int kc   = u >> 9;
    const int t    = tf * 16 + (lane & 15);
    const int s0   = kc * 32 + (lane >> 4) * 8;
    unsigned short h[8];
    #pragma unroll
    for (int j = 0; j < 8; ++j)
        h[j] = f2bf(probs[t * T_ + s0 + j]);
    uint4 pk;
    pk.x = h[0] | ((unsigned)h[1] << 16);
    pk.y = h[2] | ((unsigned)h[3] << 16);
    pk.z = h[4] | ((unsigned)h[5] << 16);
    pk.w = h[6] | ((unsigned)h[7] << 16);
    *(uint4*)&Pfrag[u * 8] = pk;
}

// ---------------------------------------------------------------------------
// Kernel E1: per-snapshot histogram over 4096 cell-buckets. cntT[s][b].
// ---------------------------------------------------------------------------
__global__ __launch_bounds__(256)
void k_hist2(const int* __restrict__ edge_src, const int* __restrict__ edge_dst,
             int* __restrict__ cntT)
{
    __shared__ int hist[NB2_];
    const int s = blockIdx.x;
    const int tid = threadIdx.x;
    for (int i = tid; i < NB2_; i += 256) hist[i] = 0;
    __syncthreads();
    for (int e = tid; e < E_; e += 256) {
        const size_t eo = (size_t)s * E_ + e;
        const int bkt = (edge_src[eo] << 2) | (edge_dst[eo] >> 8);
        atomicAdd(&hist[bkt], 1);
    }
    __syncthreads();
    for (int i = tid; i < NB2_; i += 256) cntT[s * NB2_ + i] = hist[i];
}

// ---------------------------------------------------------------------------
// Kernel E2: per-bucket scan over s. prefS2[b][0..128] (exclusive), totB[b].
// ---------------------------------------------------------------------------
__global__ __launch_bounds__(128)
void k_scan2(const int* __restrict__ cntT, int* __restrict__ prefS2,
             int* __restrict__ totB)
{
    __shared__ int sc[T_];
    const int b = blockIdx.x;
    const int tid = threadIdx.x;
    sc[tid] = cntT[tid * NB2_ + b];
    __syncthreads();
    #pragma unroll
    for (int off = 1; off < T_; off <<= 1) {
        int v = (tid >= off) ? sc[tid - off] : 0;
        __syncthreads();
        sc[tid] += v;
        __syncthreads();
    }
    prefS2[b * PS2_ + tid + 1] = sc[tid];
    if (tid == 0) prefS2[b * PS2_] = 0;
    if (tid == T_ - 1) totB[b] = sc[tid];
}

// ---------------------------------------------------------------------------
// Kernel E3: scan 4096 bucket totals -> bucketStart (exclusive prefix).
// ---------------------------------------------------------------------------
__global__ __launch_bounds__(1024)
void k_btotal2(const int* __restrict__ totB, int* __restrict__ bucketStart)
{
    __shared__ int sc[1024];
    const int tid = threadIdx.x;
    const int4 v = *(const int4*)&totB[tid * 4];
    const int s01 = v.x + v.y, s012 = s01 + v.z;
    sc[tid] = s012 + v.w;
    __syncthreads();
    #pragma unroll
    for (int off = 1; off < 1024; off <<= 1) {
        int u = (tid >= off) ? sc[tid - off] : 0;
        __syncthreads();
        sc[tid] += u;
        __syncthreads();
    }
    const int ex = (tid > 0) ? sc[tid - 1] : 0;
    bucketStart[tid * 4 + 0] = ex;
    bucketStart[tid * 4 + 1] = ex + v.x;
    bucketStart[tid * 4 + 2] = ex + s01;
    bucketStart[tid * 4 + 3] = ex + s012;
}

// ---------------------------------------------------------------------------
// Kernel E4: scatter edges -> bucket-major sortedC: ((s<<8)|(dst&255), val)
// ---------------------------------------------------------------------------
__global__ __launch_bounds__(256)
void k_scatter2(const float* __restrict__ edge_val,
                const int* __restrict__ edge_src,
                const int* __restrict__ edge_dst,
                const int* __restrict__ prefS2,
                const int* __restrict__ bucketStart,
                uint2* __restrict__ sortedC)
{
    __shared__ int cur[NB2_];
    const int s = blockIdx.x;
    const int tid = threadIdx.x;
    for (int b = tid; b < NB2_; b += 256)
        cur[b] = bucketStart[b] + prefS2[b * PS2_ + s];
    __syncthreads();
    for (int e = tid; e < E_; e += 256) {
        const size_t eo = (size_t)s * E_ + e;
        const int src = edge_src[eo];
        const int dst = edge_dst[eo];
        const float v = edge_val[eo];
        const int bkt = (src << 2) | (dst >> 8);
        const int gidx = atomicAdd(&cur[bkt], 1);
        sortedC[gidx] = make_uint2((unsigned)((s << 8) | (dst & 255)),
                                   __float_as_uint(v));
    }
}

// ---------------------------------------------------------------------------
// Kernel E5: out[t][cell-tile] = P x A via MFMA, A built per s-chunk in LDS.
// ---------------------------------------------------------------------------
__global__ __launch_bounds__(256)
void k_accum_mfma(const unsigned short* __restrict__ Pfrag,
                  const uint2* __restrict__ sortedC,
                  const int* __restrict__ prefS2,
                  const int* __restrict__ bucketStart,
                  float* __restrict__ out)
{
    __shared__ float stage[32 * 258];       // 33 KB, [s 32][c 256+2 pad]
    __shared__ unsigned short P_l[16384];   // 32 KB fragment-linear

    const int ct   = blockIdx.x;
    const int tid  = threadIdx.x;
    const int lane = tid & 63;
    const int wv   = tid >> 6;
    const int l15  = lane & 15, l4 = lane >> 4;

    #pragma unroll
    for (int r = 0; r < 8; ++r) {
        const int off = r * 4096 + tid * 16;
        __builtin_amdgcn_global_load_lds(
            (const __attribute__((address_space(1))) unsigned int*)((const char*)Pfrag + off),
            (__attribute__((address_space(3))) unsigned int*)((char*)P_l + off),
            16, 0, 0);
    }

    const int base = bucketStart[ct];
    const int prow = ct * PS2_;

    f32x4 acc[8][4] = {};   // [tf][cf]

    for (int kc = 0; kc < 4; ++kc) {
        __syncthreads();
        for (int i = tid; i < 32 * 258; i += 256) stage[i] = 0.f;
        __syncthreads();
        const int i0 = prefS2[prow + kc * 32];
        const int i1 = prefS2[prow + kc * 32 + 32];
        for (int i = i0 + tid; i < i1; i += 256) {
            const uint2 it = sortedC[base + i];
            atomicAdd(&stage[((it.x >> 8) & 31) * 258 + (it.x & 255)],
                      __uint_as_float(it.y));
        }
        __syncthreads();

        #pragma unroll
        for (int cf = 0; cf < 4; ++cf) {
            const int c = wv * 64 + cf * 16 + l15;
            float bs[8];
            #pragma unroll
            for (int j = 0; j < 8; ++j)
                bs[j] = stage[(l4 * 8 + j) * 258 + c];
            bf16x8 bfr;
            #pragma unroll
            for (int j = 0; j < 8; ++j)
                bfr[j] = (short)f2bf(bs[j]);
            #pragma unroll
            for (int tf = 0; tf < 8; ++tf) {
                if (tf >= 2 * kc) {     // wave-uniform triangular skip
                    const bf16x8 af =
                        *(const bf16x8*)&P_l[((kc * 8 + tf) * 64 + lane) * 8];
                    acc[tf][cf] = __builtin_amdgcn_mfma_f32_16x16x32_bf16(
                        af, bfr, acc[tf][cf], 0, 0, 0);
                }
            }
        }
    }

    #pragma unroll
    for (int tf = 0; tf < 8; ++tf) {
        #pragma unroll
        for (int cf = 0; cf < 4; ++cf) {
            #pragma unroll
            for (int j = 0; j < 4; ++j) {
                const int t = tf * 16 + l4 * 4 + j;
                const size_t o = ((size_t)t << 20) + ct * 256 + wv * 64 + cf * 16 + l15;
                out[o] = acc[tf][cf][j];
            }
        }
    }
}

// ---------------------------------------------------------------------------
extern "C" void kernel_launch(void* const* d_in, const int* in_sizes, int n_in,
                              void* d_out, int out_size, void* d_ws, size_t ws_size,
                              hipStream_t stream) {
    const float* emb      = (const float*)d_in[0];
    const float* W1       = (const float*)d_in[1];
    const float* b1       = (const float*)d_in[2];
    const float* W2       = (const float*)d_in[3];
    const float* b2       = (const float*)d_in[4];
    const float* Wq       = (const float*)d_in[5];
    const float* bq       = (const float*)d_in[6];
    const float* Wk       = (const float*)d_in[7];
    const float* bk       = (const float*)d_in[8];
    const float* edge_val = (const float*)d_in[9];
    const int*   edge_src = (const int*)d_in[10];
    const int*   edge_dst = (const int*)d_in[11];
    float* out = (float*)d_out;

    // workspace layout (~19.3 MB; cntT aliased under sortedC — cntT dead
    // before k_scatter2 writes sortedC)
    char* ws = (char*)d_ws;
    float*          pool_sum    = (float*)(ws);                        // 256 KB
    unsigned int*   pool_max    = (unsigned int*)(ws + (256 << 10));   // 256 KB
    float*          q           = (float*)(ws + (640 << 10));          // 128 KB
    float*          k           = (float*)(ws + (768 << 10));          // 128 KB
    float*          probs       = (float*)(ws + (896 << 10));          // 64 KB
    unsigned short* W1S         = (unsigned short*)(ws + (960 << 10)); // 256 KB
    unsigned short* Pfrag       = (unsigned short*)(ws + (1216 << 10));// 32 KB
    int*            prefS2      = (int*)(ws + (1248 << 10));           // 2064 KB
    int*            totB        = (int*)(ws + (3312 << 10));           // 16 KB
    int*            bucketStart = (int*)(ws + (3328 << 10));           // 16 KB
    int*            cntT        = (int*)(ws + (3344 << 10));           // 2 MB (aliased)
    uint2*          sortedC     = (uint2*)(ws + (3344 << 10));         // 16 MB

    hipMemsetAsync(d_ws, 0, 512 << 10, stream);   // zero pool accumulators

    // edge sort chain
    k_hist2<<<T_, 256, 0, stream>>>(edge_src, edge_dst, cntT);
    k_scan2<<<NB2_, 128, 0, stream>>>(cntT, prefS2, totB);
    k_btotal2<<<1, 1024, 0, stream>>>(totB, bucketStart);
    k_scatter2<<<T_, 256, 0, stream>>>(edge_val, edge_src, edge_dst,
                                       prefS2, bucketStart, sortedC);

    // MLP -> attention probs chain
    k_w1cast<<<64, 256, 0, stream>>>(W1, W1S);
    k_mlp1_mfma<<<2048, 512, 0, stream>>>(emb, W1S, b1, pool_sum, pool_max);
    k_mlp2qk<<<128, 256, 0, stream>>>(pool_sum, pool_max, W2, b2,
                                      Wq, bq, Wk, bk, q, k);
    k_probs<<<128, 128, 0, stream>>>(q, k, probs);
    k_pcast<<<8, 256, 0, stream>>>(probs, Pfrag);

    // stage E: P x A as MFMA GEMM over LDS-materialized A tiles
    k_accum_mfma<<<NB2_, 256, 0, stream>>>(Pfrag, sortedC, prefS2,
                                           bucketStart, out);
}

// Round 8
// 396.102 us; speedup vs baseline: 1.1443x; 1.1443x over previous
//
#include <hip/hip_runtime.h>
#include <hip/hip_bf16.h>

#define T_ 128
#define N_ 1024
#define E_ 16384
#define D_ 256
#define H_ 8
#define D2_ 512    // 2*D
#define NB2_ 4096  // cell buckets: bucket = src*4 + (dst>>8), 256 cells each
#define PS2_ 129   // prefS2 row stride

typedef __attribute__((ext_vector_type(8))) short bf16x8;
typedef __attribute__((ext_vector_type(4))) float f32x4;

__device__ __forceinline__ void atomAddF(float* p, float v) {
#if defined(__HIP_PLATFORM_AMD__)
    unsafeAtomicAdd(p, v);
#else
    atomicAdd(p, v);
#endif
}

__device__ __forceinline__ unsigned short f2bf(float x) {
    return __bfloat16_as_ushort(__float2bfloat16(x));
}

// ---------------------------------------------------------------------------
// Kernel A0: cast W1 (f32 [256][512]) to bf16 in B-fragment-linear layout:
// W1S[(k8*512 + col)*8 + (k&7)]
// ---------------------------------------------------------------------------
__global__ __launch_bounds__(256)
void k_w1cast(const float* __restrict__ W1, unsigned short* __restrict__ W1S)
{
    const int u   = blockIdx.x * 256 + threadIdx.x;  // 0..16383
    const int col = u & 511;
    const int k8  = u >> 9;                          // 0..31
    unsigned short h[8];
    #pragma unroll
    for (int j = 0; j < 8; ++j)
        h[j] = f2bf(W1[(size_t)(k8 * 8 + j) * D2_ + col]);
    uint4 pk;
    pk.x = h[0] | ((unsigned)h[1] << 16);
    pk.y = h[2] | ((unsigned)h[3] << 16);
    pk.z = h[4] | ((unsigned)h[5] << 16);
    pk.w = h[6] | ((unsigned)h[7] << 16);
    *(uint4*)&W1S[(size_t)k8 * 4096 + col * 8] = pk;
}

// ---------------------------------------------------------------------------
// Kernel A: bf16 MFMA GEMM  h = relu(emb@W1+b1), fused in-register pooling.
// LDS-staged (round-6 version — direct-global B regressed +50us in round 7:
// per-MFMA L2 latency beats global_load_lds staging).
// ---------------------------------------------------------------------------
__global__ __launch_bounds__(512)
void k_mlp1_mfma(const float* __restrict__ emb,
                 const unsigned short* __restrict__ W1S,
                 const float* __restrict__ b1,
                 float* __restrict__ pool_sum,        // [T][512]
                 unsigned int* __restrict__ pool_max) // [T][512] float-as-uint
{
    __shared__ unsigned short A_l[2048];   // [4 kb][64 row][8]  4 KB
    __shared__ unsigned short B_l[16384];  // [4 kb][512 col][8] 32 KB

    const int tid  = threadIdx.x;
    const int lane = tid & 63;
    const int wave = tid >> 6;
    const int wm = wave >> 2, wn = wave & 3;   // 2 x 4 wave grid
    const int l15 = lane & 15, l4 = lane >> 4;
    const int r0 = blockIdx.x * 64;            // global row = t*1024 + n
    const int t  = blockIdx.x >> 4;

    f32x4 acc[2][8] = {};

    for (int ks = 0; ks < 8; ++ks) {
        {
            const int row = tid >> 3, k4 = tid & 7;
            const float4 v = *(const float4*)&emb[(size_t)(r0 + row) * D_ + ks * 32 + k4 * 4];
            uint2 pk;
            pk.x = f2bf(v.x) | ((unsigned)f2bf(v.y) << 16);
            pk.y = f2bf(v.z) | ((unsigned)f2bf(v.w) << 16);
            *(uint2*)&A_l[(k4 >> 1) * 512 + row * 8 + (k4 & 1) * 4] = pk;
        }
        {
            const char* gsrc = (const char*)W1S + (size_t)ks * 32768;
            #pragma unroll
            for (int r = 0; r < 4; ++r) {
                const int off = r * 8192 + tid * 16;
                __builtin_amdgcn_global_load_lds(
                    (const __attribute__((address_space(1))) unsigned int*)(gsrc + off),
                    (__attribute__((address_space(3))) unsigned int*)((char*)B_l + off),
                    16, 0, 0);
            }
        }
        __syncthreads();

        const bf16x8 a0 = *(const bf16x8*)&A_l[l4 * 512 + (wm * 32 + l15) * 8];
        const bf16x8 a1 = *(const bf16x8*)&A_l[l4 * 512 + (wm * 32 + 16 + l15) * 8];
        #pragma unroll
        for (int cf = 0; cf < 8; ++cf) {
            const bf16x8 b = *(const bf16x8*)&B_l[l4 * 4096 + (wn * 128 + cf * 16 + l15) * 8];
            acc[0][cf] = __builtin_amdgcn_mfma_f32_16x16x32_bf16(a0, b, acc[0][cf], 0, 0, 0);
            acc[1][cf] = __builtin_amdgcn_mfma_f32_16x16x32_bf16(a1, b, acc[1][cf], 0, 0, 0);
        }
        __syncthreads();
    }

    #pragma unroll
    for (int cf = 0; cf < 8; ++cf) {
        const int col = wn * 128 + cf * 16 + l15;
        const float bias = b1[col];
        float cs = 0.f, cm = 0.f;
        #pragma unroll
        for (int mf = 0; mf < 2; ++mf) {
            #pragma unroll
            for (int j = 0; j < 4; ++j) {
                float h = acc[mf][cf][j] + bias;
                h = fmaxf(h, 0.f);
                cs += h;
                cm = fmaxf(cm, h);
            }
        }
        cs += __shfl_xor(cs, 16);
        cs += __shfl_xor(cs, 32);
        cm = fmaxf(cm, __shfl_xor(cm, 16));
        cm = fmaxf(cm, __shfl_xor(cm, 32));
        if (l4 == 0) {
            atomAddF(pool_sum + t * D2_ + col, cs);
            atomicMax(pool_max + t * D2_ + col, __float_as_uint(cm));
        }
    }
}

// ---------------------------------------------------------------------------
// Kernel B+C fused: pooled -> x (LDS only) -> q,k
// ---------------------------------------------------------------------------
__global__ __launch_bounds__(256)
void k_mlp2qk(const float* __restrict__ pool_sum,
              const unsigned int* __restrict__ pool_max,
              const float* __restrict__ W2, const float* __restrict__ b2,
              const float* __restrict__ Wq, const float* __restrict__ bq,
              const float* __restrict__ Wk, const float* __restrict__ bk,
              float* __restrict__ q, float* __restrict__ k)
{
    __shared__ float pl[D2_];
    __shared__ float xl[D_];
    const int t = blockIdx.x;
    const int j = threadIdx.x;

    pl[j]       = pool_sum[t * D2_ + j]       * (1.0f / (float)N_) +
                  __uint_as_float(pool_max[t * D2_ + j]);
    pl[j + 256] = pool_sum[t * D2_ + j + 256] * (1.0f / (float)N_) +
                  __uint_as_float(pool_max[t * D2_ + j + 256]);
    __syncthreads();

    float acc = b2[j];
    for (int kk = 0; kk < D2_; ++kk)
        acc += pl[kk] * W2[(size_t)kk * D_ + j];
    acc = fmaxf(acc, 0.f);

    const int i2 = (j >> 1) * 2;
    const float div = expf((float)i2 * (-logf(10000.0f) / (float)D_));
    const float ang = (float)t * div;
    acc += (j & 1) ? cosf(ang) : sinf(ang);
    xl[j] = acc;
    __syncthreads();

    float aq = bq[j], ak = bk[j];
    for (int kk = 0; kk < D_; ++kk) {
        const float xv = xl[kk];
        aq += xv * Wq[(size_t)kk * D_ + j];
        ak += xv * Wk[(size_t)kk * D_ + j];
    }
    q[t * D_ + j] = aq * 0.17677669529663687f;  // (D/H)^-0.5
    k[t * D_ + j] = ak;
}

// ---------------------------------------------------------------------------
// Kernel D: scores -> per-head softmax -> mean heads -> threshold/identity/tril
// ---------------------------------------------------------------------------
__global__ __launch_bounds__(128)
void k_probs(const float* __restrict__ q,
             const float* __restrict__ k,
             float* __restrict__ probs)
{
    __shared__ float ql[D_];
    __shared__ float red[128];
    const int qt = blockIdx.x;
    const int kt = threadIdx.x;

    ql[kt]       = q[qt * D_ + kt];
    ql[kt + 128] = q[qt * D_ + kt + 128];
    __syncthreads();

    float sh[H_];
    #pragma unroll
    for (int h = 0; h < H_; ++h) {
        float s = 0.f;
        #pragma unroll
        for (int d = 0; d < 32; ++d)
            s += ql[h * 32 + d] * k[kt * D_ + h * 32 + d];
        sh[h] = s;
    }

    float pm = 0.f;
    for (int h = 0; h < H_; ++h) {
        red[kt] = sh[h]; __syncthreads();
        for (int off = 64; off > 0; off >>= 1) {
            if (kt < off) red[kt] = fmaxf(red[kt], red[kt + off]);
            __syncthreads();
        }
        const float m = red[0]; __syncthreads();
        const float e = expf(sh[h] - m);
        red[kt] = e; __syncthreads();
        for (int off = 64; off > 0; off >>= 1) {
            if (kt < off) red[kt] += red[kt + off];
            __syncthreads();
        }
        const float Z = red[0]; __syncthreads();
        pm += e / Z;
    }
    pm *= (1.0f / (float)H_);

    if (pm < (1.0f / (float)T_)) pm = 0.f;
    if (kt == qt) pm += 1.0f;
    if (kt > qt) pm = 0.f;
    probs[qt * T_ + kt] = pm;
}

// ---------------------------------------------------------------------------
// Kernel D2: pack probs f32 -> bf16 a-fragment-linear Pfrag[kc][tf][lane][8]
// ---------------------------------------------------------------------------
__global__ __launch_bounds__(256)
void k_pcast(const float* __restrict__ probs, unsigned short* __restrict__ Pfrag)
{
    const int u    = blockIdx.x * 256 + threadIdx.x;  // 0..2047
    const int lane = u & 63;
    const int tf   = (u >> 6) & 7;
    const int kc   = u >> 9;
    const int t    = tf * 16 + (lane & 15);
    const int s0   = kc * 32 + (lane >> 4) * 8;
    unsigned short h[8];
    #pragma unroll
    for (int j = 0; j < 8; ++j)
        h[j] = f2bf(probs[t * T_ + s0 + j]);
    uint4 pk;
    pk.x = h[0] | ((unsigned)h[1] << 16);
    pk.y = h[2] | ((unsigned)h[3] << 16);
    pk.z = h[4] | ((unsigned)h[5] << 16);
    pk.w = h[6] | ((unsigned)h[7] << 16);
    *(uint4*)&Pfrag[u * 8] = pk;
}

// ---------------------------------------------------------------------------
// Kernel E1: per-snapshot histogram over 4096 cell-buckets. cntT[s][b].
// ---------------------------------------------------------------------------
__global__ __launch_bounds__(256)
void k_hist2(const int* __restrict__ edge_src, const int* __restrict__ edge_dst,
             int* __restrict__ cntT)
{
    __shared__ int hist[NB2_];
    const int s = blockIdx.x;
    const int tid = threadIdx.x;
    for (int i = tid; i < NB2_; i += 256) hist[i] = 0;
    __syncthreads();
    for (int e = tid; e < E_; e += 256) {
        const size_t eo = (size_t)s * E_ + e;
        const int bkt = (edge_src[eo] << 2) | (edge_dst[eo] >> 8);
        atomicAdd(&hist[bkt], 1);
    }
    __syncthreads();
    for (int i = tid; i < NB2_; i += 256) cntT[s * NB2_ + i] = hist[i];
}

// ---------------------------------------------------------------------------
// Kernel E2: per-bucket scan over s. prefS2[b][0..128] (exclusive), totB[b].
// ---------------------------------------------------------------------------
__global__ __launch_bounds__(128)
void k_scan2(const int* __restrict__ cntT, int* __restrict__ prefS2,
             int* __restrict__ totB)
{
    __shared__ int sc[T_];
    const int b = blockIdx.x;
    const int tid = threadIdx.x;
    sc[tid] = cntT[tid * NB2_ + b];
    __syncthreads();
    #pragma unroll
    for (int off = 1; off < T_; off <<= 1) {
        int v = (tid >= off) ? sc[tid - off] : 0;
        __syncthreads();
        sc[tid] += v;
        __syncthreads();
    }
    prefS2[b * PS2_ + tid + 1] = sc[tid];
    if (tid == 0) prefS2[b * PS2_] = 0;
    if (tid == T_ - 1) totB[b] = sc[tid];
}

// ---------------------------------------------------------------------------
// Kernel E3: scan 4096 bucket totals -> bucketStart (exclusive prefix).
// ---------------------------------------------------------------------------
__global__ __launch_bounds__(1024)
void k_btotal2(const int* __restrict__ totB, int* __restrict__ bucketStart)
{
    __shared__ int sc[1024];
    const int tid = threadIdx.x;
    const int4 v = *(const int4*)&totB[tid * 4];
    const int s01 = v.x + v.y, s012 = s01 + v.z;
    sc[tid] = s012 + v.w;
    __syncthreads();
    #pragma unroll
    for (int off = 1; off < 1024; off <<= 1) {
        int u = (tid >= off) ? sc[tid - off] : 0;
        __syncthreads();
        sc[tid] += u;
        __syncthreads();
    }
    const int ex = (tid > 0) ? sc[tid - 1] : 0;
    bucketStart[tid * 4 + 0] = ex;
    bucketStart[tid * 4 + 1] = ex + v.x;
    bucketStart[tid * 4 + 2] = ex + s01;
    bucketStart[tid * 4 + 3] = ex + s012;
}

// ---------------------------------------------------------------------------
// Kernel E4: scatter edges -> bucket-major sortedC: ((s<<8)|(dst&255), val)
// ---------------------------------------------------------------------------
__global__ __launch_bounds__(256)
void k_scatter2(const float* __restrict__ edge_val,
                const int* __restrict__ edge_src,
                const int* __restrict__ edge_dst,
                const int* __restrict__ prefS2,
                const int* __restrict__ bucketStart,
                uint2* __restrict__ sortedC)
{
    __shared__ int cur[NB2_];
    const int s = blockIdx.x;
    const int tid = threadIdx.x;
    for (int b = tid; b < NB2_; b += 256)
        cur[b] = bucketStart[b] + prefS2[b * PS2_ + s];
    __syncthreads();
    for (int e = tid; e < E_; e += 256) {
        const size_t eo = (size_t)s * E_ + e;
        const int src = edge_src[eo];
        const int dst = edge_dst[eo];
        const float v = edge_val[eo];
        const int bkt = (src << 2) | (dst >> 8);
        const int gidx = atomicAdd(&cur[bkt], 1);
        sortedC[gidx] = make_uint2((unsigned)((s << 8) | (dst & 255)),
                                   __float_as_uint(v));
    }
}

// ---------------------------------------------------------------------------
// Kernel E5: out[t][cell-tile] = P x A via MFMA, A built per s-chunk in LDS.
// kc phases use stage as [32][258] f32; epilogue reuses it as [16][260] to
// transpose C-fragments so each wave stores 1KB contiguous (float4/lane).
// ---------------------------------------------------------------------------
__global__ __launch_bounds__(256)
void k_accum_mfma(const unsigned short* __restrict__ Pfrag,
                  const uint2* __restrict__ sortedC,
                  const int* __restrict__ prefS2,
                  const int* __restrict__ bucketStart,
                  float* __restrict__ out)
{
    __shared__ float stage[32 * 258];       // 33 KB (>= 16*260 for epilogue)
    __shared__ unsigned short P_l[16384];   // 32 KB fragment-linear

    const int ct   = blockIdx.x;
    const int tid  = threadIdx.x;
    const int lane = tid & 63;
    const int wv   = tid >> 6;
    const int l15  = lane & 15, l4 = lane >> 4;

    #pragma unroll
    for (int r = 0; r < 8; ++r) {
        const int off = r * 4096 + tid * 16;
        __builtin_amdgcn_global_load_lds(
            (const __attribute__((address_space(1))) unsigned int*)((const char*)Pfrag + off),
            (__attribute__((address_space(3))) unsigned int*)((char*)P_l + off),
            16, 0, 0);
    }

    const int base = bucketStart[ct];
    const int prow = ct * PS2_;

    f32x4 acc[8][4] = {};   // [tf][cf]

    for (int kc = 0; kc < 4; ++kc) {
        __syncthreads();
        {   // vectorized zero: 8256 floats = 2064 float4
            float4* s4 = (float4*)stage;
            for (int i = tid; i < 2064; i += 256)
                s4[i] = make_float4(0.f, 0.f, 0.f, 0.f);
        }
        __syncthreads();
        const int i0 = prefS2[prow + kc * 32];
        const int i1 = prefS2[prow + kc * 32 + 32];
        for (int i = i0 + tid; i < i1; i += 256) {
            const uint2 it = sortedC[base + i];
            atomicAdd(&stage[((it.x >> 8) & 31) * 258 + (it.x & 255)],
                      __uint_as_float(it.y));
        }
        __syncthreads();

        #pragma unroll
        for (int cf = 0; cf < 4; ++cf) {
            const int c = wv * 64 + cf * 16 + l15;
            float bs[8];
            #pragma unroll
            for (int j = 0; j < 8; ++j)
                bs[j] = stage[(l4 * 8 + j) * 258 + c];
            bf16x8 bfr;
            #pragma unroll
            for (int j = 0; j < 8; ++j)
                bfr[j] = (short)f2bf(bs[j]);
            #pragma unroll
            for (int tf = 0; tf < 8; ++tf) {
                if (tf >= 2 * kc) {     // wave-uniform triangular skip
                    const bf16x8 af =
                        *(const bf16x8*)&P_l[((kc * 8 + tf) * 64 + lane) * 8];
                    acc[tf][cf] = __builtin_amdgcn_mfma_f32_16x16x32_bf16(
                        af, bfr, acc[tf][cf], 0, 0, 0);
                }
            }
        }
    }

    // epilogue: per tf-slab, transpose via LDS [16][260] then store 1KB/wave
    const int erow = tid >> 6;            // 0..3 (row group per pass)
    const int ecol = (tid & 63) * 4;      // float4 col
    #pragma unroll
    for (int tf = 0; tf < 8; ++tf) {
        __syncthreads();                  // stage free (prev readers done)
        #pragma unroll
        for (int cf = 0; cf < 4; ++cf) {
            const int c = wv * 64 + cf * 16 + l15;
            #pragma unroll
            for (int j = 0; j < 4; ++j)
                stage[(l4 * 4 + j) * 260 + c] = acc[tf][cf][j];
        }
        __syncthreads();
        #pragma unroll
        for (int ii = 0; ii < 4; ++ii) {
            const int row = ii * 4 + erow;   // 0..15
            const float4 v = *(const float4*)&stage[row * 260 + ecol];
            *(float4*)&out[((size_t)(tf * 16 + row) << 20) + ct * 256 + ecol] = v;
        }
    }
}

// ---------------------------------------------------------------------------
extern "C" void kernel_launch(void* const* d_in, const int* in_sizes, int n_in,
                              void* d_out, int out_size, void* d_ws, size_t ws_size,
                              hipStream_t stream) {
    const float* emb      = (const float*)d_in[0];
    const float* W1       = (const float*)d_in[1];
    const float* b1       = (const float*)d_in[2];
    const float* W2       = (const float*)d_in[3];
    const float* b2       = (const float*)d_in[4];
    const float* Wq       = (const float*)d_in[5];
    const float* bq       = (const float*)d_in[6];
    const float* Wk       = (const float*)d_in[7];
    const float* bk       = (const float*)d_in[8];
    const float* edge_val = (const float*)d_in[9];
    const int*   edge_src = (const int*)d_in[10];
    const int*   edge_dst = (const int*)d_in[11];
    float* out = (float*)d_out;

    // workspace layout (~19.3 MB; cntT aliased under sortedC — cntT dead
    // before k_scatter2 writes sortedC)
    char* ws = (char*)d_ws;
    float*          pool_sum    = (float*)(ws);                        // 256 KB
    unsigned int*   pool_max    = (unsigned int*)(ws + (256 << 10));   // 256 KB
    float*          q           = (float*)(ws + (640 << 10));          // 128 KB
    float*          k           = (float*)(ws + (768 << 10));          // 128 KB
    float*          probs       = (float*)(ws + (896 << 10));          // 64 KB
    unsigned short* W1S         = (unsigned short*)(ws + (960 << 10)); // 256 KB
    unsigned short* Pfrag       = (unsigned short*)(ws + (1216 << 10));// 32 KB
    int*            prefS2      = (int*)(ws + (1248 << 10));           // 2064 KB
    int*            totB        = (int*)(ws + (3312 << 10));           // 16 KB
    int*            bucketStart = (int*)(ws + (3328 << 10));           // 16 KB
    int*            cntT        = (int*)(ws + (3344 << 10));           // 2 MB (aliased)
    uint2*          sortedC     = (uint2*)(ws + (3344 << 10));         // 16 MB

    hipMemsetAsync(d_ws, 0, 512 << 10, stream);   // zero pool accumulators

    // edge sort chain
    k_hist2<<<T_, 256, 0, stream>>>(edge_src, edge_dst, cntT);
    k_scan2<<<NB2_, 128, 0, stream>>>(cntT, prefS2, totB);
    k_btotal2<<<1, 1024, 0, stream>>>(totB, bucketStart);
    k_scatter2<<<T_, 256, 0, stream>>>(edge_val, edge_src, edge_dst,
                                       prefS2, bucketStart, sortedC);

    // MLP -> attention probs chain
    k_w1cast<<<64, 256, 0, stream>>>(W1, W1S);
    k_mlp1_mfma<<<2048, 512, 0, stream>>>(emb, W1S, b1, pool_sum, pool_max);
    k_mlp2qk<<<128, 256, 0, stream>>>(pool_sum, pool_max, W2, b2,
                                      Wq, bq, Wk, bk, q, k);
    k_probs<<<128, 128, 0, stream>>>(q, k, probs);
    k_pcast<<<8, 256, 0, stream>>>(probs, Pfrag);

    // stage E: P x A as MFMA GEMM over LDS-materialized A tiles
    k_accum_mfma<<<NB2_, 256, 0, stream>>>(Pfrag, sortedC, prefS2,
                                           bucketStart, out);
}

// Round 9
// 358.514 us; speedup vs baseline: 1.2642x; 1.1048x over previous
//
#include <hip/hip_runtime.h>
#include <hip/hip_bf16.h>

#define T_ 128
#define N_ 1024
#define E_ 16384
#define D_ 256
#define H_ 8
#define D2_ 512    // 2*D
#define NB2_ 4096  // cell buckets: bucket = src*4 + (dst>>8), 256 cells each
#define PS3_ 257   // prefS3 row stride (256 (s,half) slots + 1)

typedef __attribute__((ext_vector_type(8))) short bf16x8;
typedef __attribute__((ext_vector_type(4))) float f32x4;

__device__ __forceinline__ void atomAddF(float* p, float v) {
#if defined(__HIP_PLATFORM_AMD__)
    unsafeAtomicAdd(p, v);
#else
    atomicAdd(p, v);
#endif
}

__device__ __forceinline__ unsigned short f2bf(float x) {
    return __bfloat16_as_ushort(__float2bfloat16(x));
}

// ---------------------------------------------------------------------------
// Kernel 1: k_prep — fused pool-zero + W1 bf16 fragment-cast + edge histogram.
// grid 256 (= 2 blocks per snapshot s), block 256.
// cnt layout: [b][slot], slot = s*2 + half  (scan3 reads coalesced).
// ---------------------------------------------------------------------------
__global__ __launch_bounds__(256)
void k_prep(const float* __restrict__ W1, unsigned short* __restrict__ W1S,
            const int* __restrict__ edge_src, const int* __restrict__ edge_dst,
            float4* __restrict__ poolz, int* __restrict__ cnt)
{
    __shared__ int hist[NB2_];
    const int bi = blockIdx.x, tid = threadIdx.x;
    const int s = bi >> 1, h = bi & 1;

    // pool accumulator zero: 256 blocks x 128 float4 = 512 KB
    if (tid < 128) poolz[bi * 128 + tid] = make_float4(0.f, 0.f, 0.f, 0.f);

    // W1 cast: 256 blocks x 64 jobs = 16384
    if (tid < 64) {
        const int u   = bi * 64 + tid;
        const int col = u & 511;
        const int k8  = u >> 9;
        unsigned short hh[8];
        #pragma unroll
        for (int j = 0; j < 8; ++j)
            hh[j] = f2bf(W1[(size_t)(k8 * 8 + j) * D2_ + col]);
        uint4 pk;
        pk.x = hh[0] | ((unsigned)hh[1] << 16);
        pk.y = hh[2] | ((unsigned)hh[3] << 16);
        pk.z = hh[4] | ((unsigned)hh[5] << 16);
        pk.w = hh[6] | ((unsigned)hh[7] << 16);
        *(uint4*)&W1S[(size_t)k8 * 4096 + col * 8] = pk;
    }

    // histogram over this block's half of snapshot s
    for (int i = tid; i < NB2_; i += 256) hist[i] = 0;
    __syncthreads();
    const int e0 = h * 8192;
    for (int e = e0 + tid; e < e0 + 8192; e += 256) {
        const size_t eo = (size_t)s * E_ + e;
        atomicAdd(&hist[(edge_src[eo] << 2) | (edge_dst[eo] >> 8)], 1);
    }
    __syncthreads();
    const int slot = (s << 1) | h;
    for (int i = tid; i < NB2_; i += 256) cnt[i * 256 + slot] = hist[i];
}

// ---------------------------------------------------------------------------
// Kernel 2: bf16 MFMA GEMM  h = relu(emb@W1+b1), fused in-register pooling.
// (round-6 proven structure, unchanged)
// ---------------------------------------------------------------------------
__global__ __launch_bounds__(512)
void k_mlp1_mfma(const float* __restrict__ emb,
                 const unsigned short* __restrict__ W1S,
                 const float* __restrict__ b1,
                 float* __restrict__ pool_sum,        // [T][512]
                 unsigned int* __restrict__ pool_max) // [T][512] float-as-uint
{
    __shared__ unsigned short A_l[2048];   // [4 kb][64 row][8]  4 KB
    __shared__ unsigned short B_l[16384];  // [4 kb][512 col][8] 32 KB

    const int tid  = threadIdx.x;
    const int lane = tid & 63;
    const int wave = tid >> 6;
    const int wm = wave >> 2, wn = wave & 3;   // 2 x 4 wave grid
    const int l15 = lane & 15, l4 = lane >> 4;
    const int r0 = blockIdx.x * 64;            // global row = t*1024 + n
    const int t  = blockIdx.x >> 4;

    f32x4 acc[2][8] = {};

    for (int ks = 0; ks < 8; ++ks) {
        {
            const int row = tid >> 3, k4 = tid & 7;
            const float4 v = *(const float4*)&emb[(size_t)(r0 + row) * D_ + ks * 32 + k4 * 4];
            uint2 pk;
            pk.x = f2bf(v.x) | ((unsigned)f2bf(v.y) << 16);
            pk.y = f2bf(v.z) | ((unsigned)f2bf(v.w) << 16);
            *(uint2*)&A_l[(k4 >> 1) * 512 + row * 8 + (k4 & 1) * 4] = pk;
        }
        {
            const char* gsrc = (const char*)W1S + (size_t)ks * 32768;
            #pragma unroll
            for (int r = 0; r < 4; ++r) {
                const int off = r * 8192 + tid * 16;
                __builtin_amdgcn_global_load_lds(
                    (const __attribute__((address_space(1))) unsigned int*)(gsrc + off),
                    (__attribute__((address_space(3))) unsigned int*)((char*)B_l + off),
                    16, 0, 0);
            }
        }
        __syncthreads();

        const bf16x8 a0 = *(const bf16x8*)&A_l[l4 * 512 + (wm * 32 + l15) * 8];
        const bf16x8 a1 = *(const bf16x8*)&A_l[l4 * 512 + (wm * 32 + 16 + l15) * 8];
        #pragma unroll
        for (int cf = 0; cf < 8; ++cf) {
            const bf16x8 b = *(const bf16x8*)&B_l[l4 * 4096 + (wn * 128 + cf * 16 + l15) * 8];
            acc[0][cf] = __builtin_amdgcn_mfma_f32_16x16x32_bf16(a0, b, acc[0][cf], 0, 0, 0);
            acc[1][cf] = __builtin_amdgcn_mfma_f32_16x16x32_bf16(a1, b, acc[1][cf], 0, 0, 0);
        }
        __syncthreads();
    }

    #pragma unroll
    for (int cf = 0; cf < 8; ++cf) {
        const int col = wn * 128 + cf * 16 + l15;
        const float bias = b1[col];
        float cs = 0.f, cm = 0.f;
        #pragma unroll
        for (int mf = 0; mf < 2; ++mf) {
            #pragma unroll
            for (int j = 0; j < 4; ++j) {
                float hh = acc[mf][cf][j] + bias;
                hh = fmaxf(hh, 0.f);
                cs += hh;
                cm = fmaxf(cm, hh);
            }
        }
        cs += __shfl_xor(cs, 16);
        cs += __shfl_xor(cs, 32);
        cm = fmaxf(cm, __shfl_xor(cm, 16));
        cm = fmaxf(cm, __shfl_xor(cm, 32));
        if (l4 == 0) {
            atomAddF(pool_sum + t * D2_ + col, cs);
            atomicMax(pool_max + t * D2_ + col, __float_as_uint(cm));
        }
    }
}

// ---------------------------------------------------------------------------
// Kernel 3: per-bucket scan over 256 (s,half) slots. prefS3[b][0..256] ushort,
// totB[b]. grid 4096, block 256 (one thread per slot).
// ---------------------------------------------------------------------------
__global__ __launch_bounds__(256)
void k_scan3(const int* __restrict__ cnt, unsigned short* __restrict__ prefS3,
             int* __restrict__ totB)
{
    __shared__ int sc[256];
    const int b = blockIdx.x, tid = threadIdx.x;
    sc[tid] = cnt[b * 256 + tid];
    __syncthreads();
    #pragma unroll
    for (int off = 1; off < 256; off <<= 1) {
        int v = (tid >= off) ? sc[tid - off] : 0;
        __syncthreads();
        sc[tid] += v;
        __syncthreads();
    }
    prefS3[b * PS3_ + tid + 1] = (unsigned short)sc[tid];
    if (tid == 0)   prefS3[b * PS3_] = 0;
    if (tid == 255) totB[b] = sc[255];
}

// ---------------------------------------------------------------------------
// Kernel 4: scatter edges -> bucket-major sortedC. grid 256 (2 per s).
// Each block locally scans totB[4096] (LDS Hillis-Steele) for bucket starts;
// block 0 also emits segB[b][5] = absolute (bucket, kc-chunk) bounds.
// ---------------------------------------------------------------------------
__global__ __launch_bounds__(256)
void k_scatter3(const float* __restrict__ edge_val,
                const int* __restrict__ edge_src,
                const int* __restrict__ edge_dst,
                const unsigned short* __restrict__ prefS3,
                const int* __restrict__ totB,
                int* __restrict__ segB,
                uint2* __restrict__ sortedC)
{
    __shared__ int bst[NB2_];   // 16 KB
    const int bi = blockIdx.x, tid = threadIdx.x;
    const int s = bi >> 1, h = bi & 1;
    const int slot = (s << 1) | h;

    int orig[16];
    #pragma unroll
    for (int r = 0; r < 16; ++r) {
        const int i = r * 256 + tid;
        orig[r] = totB[i];
        bst[i] = orig[r];
    }
    __syncthreads();
    for (int off = 1; off < NB2_; off <<= 1) {
        int tmp[16];
        #pragma unroll
        for (int r = 0; r < 16; ++r) {
            const int i = r * 256 + tid;
            tmp[r] = (i >= off) ? bst[i - off] : 0;
        }
        __syncthreads();
        #pragma unroll
        for (int r = 0; r < 16; ++r) bst[r * 256 + tid] += tmp[r];
        __syncthreads();
    }
    // bst = inclusive scan; build per-bucket write cursor for this slot
    #pragma unroll
    for (int r = 0; r < 16; ++r) {
        const int i = r * 256 + tid;
        const int excl = bst[i] - orig[r];
        if (bi == 0) {
            #pragma unroll
            for (int kcx = 0; kcx < 5; ++kcx)
                segB[i * 5 + kcx] = excl + (int)prefS3[i * PS3_ + kcx * 64];
        }
        bst[i] = excl + (int)prefS3[i * PS3_ + slot];
    }
    __syncthreads();

    const int e0 = h * 8192;
    for (int e = e0 + tid; e < e0 + 8192; e += 256) {
        const size_t eo = (size_t)s * E_ + e;
        const int src = edge_src[eo];
        const int dst = edge_dst[eo];
        const float v = edge_val[eo];
        const int bkt = (src << 2) | (dst >> 8);
        const int gidx = atomicAdd(&bst[bkt], 1);
        sortedC[gidx] = make_uint2((unsigned)((s << 8) | (dst & 255)),
                                   __float_as_uint(v));
    }
}

// ---------------------------------------------------------------------------
// Kernel 5: pooled -> x (LDS only) -> q,k
// ---------------------------------------------------------------------------
__global__ __launch_bounds__(256)
void k_mlp2qk(const float* __restrict__ pool_sum,
              const unsigned int* __restrict__ pool_max,
              const float* __restrict__ W2, const float* __restrict__ b2,
              const float* __restrict__ Wq, const float* __restrict__ bq,
              const float* __restrict__ Wk, const float* __restrict__ bk,
              float* __restrict__ q, float* __restrict__ k)
{
    __shared__ float pl[D2_];
    __shared__ float xl[D_];
    const int t = blockIdx.x;
    const int j = threadIdx.x;

    pl[j]       = pool_sum[t * D2_ + j]       * (1.0f / (float)N_) +
                  __uint_as_float(pool_max[t * D2_ + j]);
    pl[j + 256] = pool_sum[t * D2_ + j + 256] * (1.0f / (float)N_) +
                  __uint_as_float(pool_max[t * D2_ + j + 256]);
    __syncthreads();

    float acc = b2[j];
    for (int kk = 0; kk < D2_; ++kk)
        acc += pl[kk] * W2[(size_t)kk * D_ + j];
    acc = fmaxf(acc, 0.f);

    const int i2 = (j >> 1) * 2;
    const float div = expf((float)i2 * (-logf(10000.0f) / (float)D_));
    const float ang = (float)t * div;
    acc += (j & 1) ? cosf(ang) : sinf(ang);
    xl[j] = acc;
    __syncthreads();

    float aq = bq[j], ak = bk[j];
    for (int kk = 0; kk < D_; ++kk) {
        const float xv = xl[kk];
        aq += xv * Wq[(size_t)kk * D_ + j];
        ak += xv * Wk[(size_t)kk * D_ + j];
    }
    q[t * D_ + j] = aq * 0.17677669529663687f;  // (D/H)^-0.5
    k[t * D_ + j] = ak;
}

// ---------------------------------------------------------------------------
// Kernel 6: scores -> per-head softmax -> mean heads -> threshold/eye/tril
// ---------------------------------------------------------------------------
__global__ __launch_bounds__(128)
void k_probs(const float* __restrict__ q,
             const float* __restrict__ k,
             float* __restrict__ probs)
{
    __shared__ float ql[D_];
    __shared__ float red[128];
    const int qt = blockIdx.x;
    const int kt = threadIdx.x;

    ql[kt]       = q[qt * D_ + kt];
    ql[kt + 128] = q[qt * D_ + kt + 128];
    __syncthreads();

    float sh[H_];
    #pragma unroll
    for (int h = 0; h < H_; ++h) {
        float s = 0.f;
        #pragma unroll
        for (int d = 0; d < 32; ++d)
            s += ql[h * 32 + d] * k[kt * D_ + h * 32 + d];
        sh[h] = s;
    }

    float pm = 0.f;
    for (int h = 0; h < H_; ++h) {
        red[kt] = sh[h]; __syncthreads();
        for (int off = 64; off > 0; off >>= 1) {
            if (kt < off) red[kt] = fmaxf(red[kt], red[kt + off]);
            __syncthreads();
        }
        const float m = red[0]; __syncthreads();
        const float e = expf(sh[h] - m);
        red[kt] = e; __syncthreads();
        for (int off = 64; off > 0; off >>= 1) {
            if (kt < off) red[kt] += red[kt + off];
            __syncthreads();
        }
        const float Z = red[0]; __syncthreads();
        pm += e / Z;
    }
    pm *= (1.0f / (float)H_);

    if (pm < (1.0f / (float)T_)) pm = 0.f;
    if (kt == qt) pm += 1.0f;
    if (kt > qt) pm = 0.f;
    probs[qt * T_ + kt] = pm;
}

// ---------------------------------------------------------------------------
// Kernel 7: pack probs f32 -> bf16 a-fragment-linear Pfrag[kc][tf][lane][8]
// ---------------------------------------------------------------------------
__global__ __launch_bounds__(256)
void k_pcast(const float* __restrict__ probs, unsigned short* __restrict__ Pfrag)
{
    const int u    = blockIdx.x * 256 + threadIdx.x;  // 0..2047
    const int lane = u & 63;
    const int tf   = (u >> 6) & 7;
    const int kc   = u >> 9;
    const int t    = tf * 16 + (lane & 15);
    const int s0   = kc * 32 + (lane >> 4) * 8;
    unsigned short hh[8];
    #pragma unroll
    for (int j = 0; j < 8; ++j)
        hh[j] = f2bf(probs[t * T_ + s0 + j]);
    uint4 pk;
    pk.x = hh[0] | ((unsigned)hh[1] << 16);
    pk.y = hh[2] | ((unsigned)hh[3] << 16);
    pk.z = hh[4] | ((unsigned)hh[5] << 16);
    pk.w = hh[6] | ((unsigned)hh[7] << 16);
    *(uint4*)&Pfrag[u * 8] = pk;
}

// ---------------------------------------------------------------------------
// Kernel 8: out[t][cell-tile] = P x A via MFMA, A built per s-chunk in LDS.
// Segment bounds come precomputed in segB[b][5]. Epilogue transposes via LDS
// for 1KB-contiguous stores per wave.
// ---------------------------------------------------------------------------
__global__ __launch_bounds__(256)
void k_accum_mfma(const unsigned short* __restrict__ Pfrag,
                  const uint2* __restrict__ sortedC,
                  const int* __restrict__ segB,
                  float* __restrict__ out)
{
    __shared__ float stage[32 * 258];       // 33 KB (>= 16*260 for epilogue)
    __shared__ unsigned short P_l[16384];   // 32 KB fragment-linear

    const int ct   = blockIdx.x;
    const int tid  = threadIdx.x;
    const int lane = tid & 63;
    const int wv   = tid >> 6;
    const int l15  = lane & 15, l4 = lane >> 4;

    #pragma unroll
    for (int r = 0; r < 8; ++r) {
        const int off = r * 4096 + tid * 16;
        __builtin_amdgcn_global_load_lds(
            (const __attribute__((address_space(1))) unsigned int*)((const char*)Pfrag + off),
            (__attribute__((address_space(3))) unsigned int*)((char*)P_l + off),
            16, 0, 0);
    }

    const int sb = ct * 5;
    f32x4 acc[8][4] = {};   // [tf][cf]

    for (int kc = 0; kc < 4; ++kc) {
        __syncthreads();
        {   // vectorized zero: 8256 floats = 2064 float4
            float4* s4 = (float4*)stage;
            for (int i = tid; i < 2064; i += 256)
                s4[i] = make_float4(0.f, 0.f, 0.f, 0.f);
        }
        __syncthreads();
        const int i0 = segB[sb + kc];
        const int i1 = segB[sb + kc + 1];
        for (int i = i0 + tid; i < i1; i += 256) {
            const uint2 it = sortedC[i];
            atomicAdd(&stage[((it.x >> 8) & 31) * 258 + (it.x & 255)],
                      __uint_as_float(it.y));
        }
        __syncthreads();

        #pragma unroll
        for (int cf = 0; cf < 4; ++cf) {
            const int c = wv * 64 + cf * 16 + l15;
            float bs[8];
            #pragma unroll
            for (int j = 0; j < 8; ++j)
                bs[j] = stage[(l4 * 8 + j) * 258 + c];
            bf16x8 bfr;
            #pragma unroll
            for (int j = 0; j < 8; ++j)
                bfr[j] = (short)f2bf(bs[j]);
            #pragma unroll
            for (int tf = 0; tf < 8; ++tf) {
                if (tf >= 2 * kc) {     // wave-uniform triangular skip
                    const bf16x8 af =
                        *(const bf16x8*)&P_l[((kc * 8 + tf) * 64 + lane) * 8];
                    acc[tf][cf] = __builtin_amdgcn_mfma_f32_16x16x32_bf16(
                        af, bfr, acc[tf][cf], 0, 0, 0);
                }
            }
        }
    }

    // epilogue: per tf-slab, transpose via LDS [16][260] then store 1KB/wave
    const int erow = tid >> 6;            // 0..3
    const int ecol = (tid & 63) * 4;      // float4 col
    #pragma unroll
    for (int tf = 0; tf < 8; ++tf) {
        __syncthreads();
        #pragma unroll
        for (int cf = 0; cf < 4; ++cf) {
            const int c = wv * 64 + cf * 16 + l15;
            #pragma unroll
            for (int j = 0; j < 4; ++j)
                stage[(l4 * 4 + j) * 260 + c] = acc[tf][cf][j];
        }
        __syncthreads();
        #pragma unroll
        for (int ii = 0; ii < 4; ++ii) {
            const int row = ii * 4 + erow;   // 0..15
            const float4 v = *(const float4*)&stage[row * 260 + ecol];
            *(float4*)&out[((size_t)(tf * 16 + row) << 20) + ct * 256 + ecol] = v;
        }
    }
}

// ---------------------------------------------------------------------------
extern "C" void kernel_launch(void* const* d_in, const int* in_sizes, int n_in,
                              void* d_out, int out_size, void* d_ws, size_t ws_size,
                              hipStream_t stream) {
    const float* emb      = (const float*)d_in[0];
    const float* W1       = (const float*)d_in[1];
    const float* b1       = (const float*)d_in[2];
    const float* W2       = (const float*)d_in[3];
    const float* b2       = (const float*)d_in[4];
    const float* Wq       = (const float*)d_in[5];
    const float* bq       = (const float*)d_in[6];
    const float* Wk       = (const float*)d_in[7];
    const float* bk       = (const float*)d_in[8];
    const float* edge_val = (const float*)d_in[9];
    const int*   edge_src = (const int*)d_in[10];
    const int*   edge_dst = (const int*)d_in[11];
    float* out = (float*)d_out;

    // workspace layout (~19.3 MB; cnt aliased under sortedC — cnt is dead
    // before k_scatter3 writes sortedC)
    char* ws = (char*)d_ws;
    float*          pool_sum = (float*)(ws);                         // 256 KB
    unsigned int*   pool_max = (unsigned int*)(ws + (256 << 10));    // 256 KB
    float*          q        = (float*)(ws + (512 << 10));           // 128 KB
    float*          k        = (float*)(ws + (640 << 10));           // 128 KB
    float*          probs    = (float*)(ws + (768 << 10));           // 64 KB
    unsigned short* W1S      = (unsigned short*)(ws + (832 << 10));  // 256 KB
    unsigned short* Pfrag    = (unsigned short*)(ws + (1088 << 10)); // 32 KB
    int*            totB     = (int*)(ws + (1120 << 10));            // 16 KB
    int*            segB     = (int*)(ws + (1136 << 10));            // 80 KB
    unsigned short* prefS3   = (unsigned short*)(ws + (1216 << 10)); // ~2056 KB
    int*            cnt      = (int*)(ws + (3328 << 10));            // 4 MB (aliased)
    uint2*          sortedC  = (uint2*)(ws + (3328 << 10));          // 16 MB

    // 1: pool-zero + W1 cast + histogram
    k_prep<<<256, 256, 0, stream>>>(W1, W1S, edge_src, edge_dst,
                                    (float4*)pool_sum, cnt);
    // 2: MLP1 GEMM + pooling (needs W1S + zeroed pool from k_prep)
    k_mlp1_mfma<<<2048, 512, 0, stream>>>(emb, W1S, b1, pool_sum, pool_max);
    // 3: per-bucket slot scan
    k_scan3<<<NB2_, 256, 0, stream>>>(cnt, prefS3, totB);
    // 4: scatter into bucket-major order (+ segB bounds from block 0)
    k_scatter3<<<256, 256, 0, stream>>>(edge_val, edge_src, edge_dst,
                                        prefS3, totB, segB, sortedC);
    // 5-7: pooled -> x -> q,k -> probs -> Pfrag
    k_mlp2qk<<<128, 256, 0, stream>>>(pool_sum, pool_max, W2, b2,
                                      Wq, bq, Wk, bk, q, k);
    k_probs<<<128, 128, 0, stream>>>(q, k, probs);
    k_pcast<<<8, 256, 0, stream>>>(probs, Pfrag);
    // 8: P x A via MFMA
    k_accum_mfma<<<NB2_, 256, 0, stream>>>(Pfrag, sortedC, segB, out);
}